// Round 13
// baseline (306.549 us; speedup 1.0000x reference)
//
#include <hip/hip_runtime.h>
#include <hip/hip_bf16.h>

// e3nn FullyConnectedTensorProduct (128x0e+128x1o)^2 -> 128x0e+128x1o, N=4096
// R13: barrier-free main loop. 32x32x16 f16 MFMA (wave = 32n x 64w, acc 128);
//      B-fragments loaded L2->VGPR directly (no weight LDS, coalesced 1KB/instr
//      from [c][p][kb][w64][v16] layout); 2048 independent waves (2/SIMD);
//      grid = 32 tiles x 16 slices (usec8 x whalf2), 8 atomic contributors.
// ws layout: [WT f16 20MB][X1g f16 4MB][X2g f16 4MB]

typedef _Float16 f16;
typedef _Float16 f16x8 __attribute__((ext_vector_type(8)));
typedef _Float16 h2 __attribute__((ext_vector_type(2)));
typedef float f32x16 __attribute__((ext_vector_type(16)));
typedef unsigned u32;

#define WT_BYTES  (5u*4u*128u*4096u*2u)     // 20971520 B = 16 slices x 655360 el x 2B
#define X1_BYTES  (32u*8u*8192u*2u)         // 4194304  ([tile32][usec8][u16][n128][q4] f16)
#define SLICE_EL  655360u                    // 64 chunks x 10240
#define CHUNK_EL  10240u                     // [p5][kb2][w64][v16] f16 (20 KB)

__device__ __forceinline__ h2 bc(u32 x){ union{u32 u; h2 h;} c; c.u=x; return c.h; }

union F8 { h2 h[4]; f16x8 v; };
struct B10 { f16x8 v[10]; };

__device__ __forceinline__ void gl_lds16(const f16* g, f16* l) {
    __builtin_amdgcn_global_load_lds(
        (const __attribute__((address_space(1))) void*)g,
        (__attribute__((address_space(3))) void*)l,
        16, 0, 0);
}

// ---- prologue: weights f32 [u][v][w] -> WT[slice][c][p][kb][w64][v16] f16 ----
// slice = (u>>4)*2 + whalf ; c = vb*16 + (u&15) ; kb = v-16-block within chunk
__global__ __launch_bounds__(256) void pack_w_kernel(
    const float* __restrict__ w0, const float* __restrict__ w1,
    const float* __restrict__ w2, const float* __restrict__ w3,
    const float* __restrict__ w4, f16* __restrict__ wt)
{
    __shared__ float tl[64][130];
    const int b = blockIdx.x;           // 640 = 5 paths x 128 u
    const int p = b >> 7;
    const int u = b & 127;
    const int usec = u >> 4;            // 0..7
    const int uin  = u & 15;
    const float* src = (p==0)?w0:(p==1)?w1:(p==2)?w2:(p==3)?w3:w4;
    const float scale = (p==0)?1.0f:(p==4)?0.40824829046386302f:0.57735026918962576f;

    for (int h = 0; h < 2; ++h) {       // two 64-v halves
        const float* spR = src + (size_t)u*16384 + (size_t)h*8192;
        #pragma unroll
        for (int k = 0; k < 8; ++k) {
            const int e4 = (k*256 + threadIdx.x) * 4;
            const float4 v4 = *(const float4*)(spR + e4);
            const int vi = e4 >> 7, w = e4 & 127;
            tl[vi][w+0]=v4.x; tl[vi][w+1]=v4.y; tl[vi][w+2]=v4.z; tl[vi][w+3]=v4.w;
        }
        __syncthreads();
        #pragma unroll
        for (int k = 0; k < 4; ++k) {
            const int cid = k*256 + threadIdx.x;     // 0..1023 8-el groups
            const int q     = cid & 3;               // v-8-group within chunk
            const int wg    = (cid >> 2) & 127;      // global w
            const int vbh   = cid >> 9;
            const int vb    = h*2 + vbh;
            const int c     = vb*16 + uin;
            const int kb    = q >> 1;
            const int h2i   = q & 1;
            const int whalf = wg >> 6;
            const int wl    = wg & 63;
            const int s     = usec*2 + whalf;
            f16x8 t8;
            #pragma unroll
            for (int j = 0; j < 8; ++j)
                t8[j] = (f16)(tl[vbh*32 + q*8 + j][wg] * scale);
            *(f16x8*)(wt + (size_t)s*SLICE_EL + (size_t)c*CHUNK_EL
                          + p*2048 + kb*1024 + wl*16 + h2i*8) = t8;
        }
        __syncthreads();
    }
}

// ---- prologue: pack x1 -> [tile32][usec8][u16][n128][q4]; x2 -> [n][q][v] ----
__global__ __launch_bounds__(256) void pack_x_kernel(
    const float* __restrict__ x1s, const float* __restrict__ x1v,
    const float* __restrict__ x2s, const float* __restrict__ x2v,
    f16* __restrict__ x1g, f16* __restrict__ x2g)
{
    if (blockIdx.x < 128) {
        __shared__ uint2 tl[128][33];
        const int nb = blockIdx.x;      // 32-node block
        #pragma unroll
        for (int k = 0; k < 16; ++k) {
            const int idx = k*256 + threadIdx.x;    // u fast
            const int u = idx & 127, nd = idx >> 7;
            const size_t i = (size_t)(nb*32 + nd)*128 + u;
            union { f16 h[4]; uint2 u2; } tp;
            tp.h[0] = (f16)x1s[i];
            tp.h[1] = (f16)x1v[i*3 + 0];
            tp.h[2] = (f16)x1v[i*3 + 1];
            tp.h[3] = (f16)x1v[i*3 + 2];
            tl[u][nd] = tp.u2;
        }
        __syncthreads();
        uint2* og = (uint2*)x1g;
        const int t = nb >> 2, nd0 = (nb & 3) * 32;   // tile of 128 nodes
        #pragma unroll
        for (int k = 0; k < 16; ++k) {
            const int idx = k*256 + threadIdx.x;    // nd fast
            const int u = idx >> 5, nd = idx & 31;
            og[(((t*8 + (u>>4))*16 + (u&15)) << 7) + nd0 + nd] = tl[u][nd];
        }
    } else {
        const int tt = (blockIdx.x - 128)*256 + threadIdx.x;
        const int n = tt >> 7, v = tt & 127;
        const size_t b = (size_t)n*512;
        const size_t i = (size_t)n*128 + v;
        x2g[b +   0 + v] = (f16)x2s[i];
        x2g[b + 128 + v] = (f16)x2v[i*3 + 0];
        x2g[b + 256 + v] = (f16)x2v[i*3 + 1];
        x2g[b + 384 + v] = (f16)x2v[i*3 + 2];
    }
}

__device__ __forceinline__ B10 loadB(const f16* cb, int kb, int bo){
    B10 r;
    #pragma unroll
    for (int p = 0; p < 5; ++p)
        #pragma unroll
        for (int ct = 0; ct < 2; ++ct)
            r.v[p*2+ct] = *(const f16x8*)(cb + p*2048 + kb*1024 + ct*512 + bo);
    return r;
}

// ---- main: 512 WGs = 32 node-tiles(128) x 16 slices, 256 thr (4 indep waves)
// No barriers in main loop; B direct L2->VGPR; wave = 32n x 64w (32x32 MFMA).
__global__ __launch_bounds__(256, 2) void tp_main(
    const f16* __restrict__ wt, const f16* __restrict__ x1g,
    const f16* __restrict__ x2g, float* __restrict__ out)
{
    __shared__ __align__(16) f16 x1lds[8192];   // 16 KB [u16][n128][q4]

    const int tid  = threadIdx.x;
    const int lane = tid & 63;
    const int wv   = tid >> 6;       // 0..3
    const int l5   = lane & 31;
    const int kg2  = lane >> 5;

    const int b     = blockIdx.x;
    const int slice = b & 15;                     // XCD slice%8
    const int t     = b >> 4;                     // node tile 0..31
    const int usec  = slice >> 1;
    const int whalf = slice & 1;

    const f16* wbase = wt + (size_t)slice * SLICE_EL;
    const int bo = l5*16 + kg2*8;                 // per-lane B offset (els)

    // prologue: x1 slice (16KB) into LDS
    {
        const f16* src = x1g + (size_t)(t*8 + usec) * 8192;
        #pragma unroll
        for (int r = 0; r < 4; ++r)
            gl_lds16(src + r*2048 + tid*8, x1lds + r*2048 + tid*8);
    }
    __syncthreads();

    f32x16 acc[2][4];   // [ct][channel] = 128 regs
    #pragma unroll
    for (int c2 = 0; c2 < 2; ++c2)
        #pragma unroll
        for (int ch = 0; ch < 4; ++ch)
            #pragma unroll
            for (int r = 0; r < 16; ++r)
                acc[c2][ch][r] = 0.f;

    h2 xq[4][2][4];     // [q][kb][pair] = 32 regs
    const int node = wv*32 + l5;
    const f16* x2b = x2g + (size_t)(t*128 + node)*512 + kg2*8;

    const f16* cb = wbase;
    B10 B0 = loadB(cb, 0, bo);
    uint2 h1c = *(const uint2*)(x1lds + node*4);   // u=0

    for (int c = 0; c < 64; ++c) {
        const int vb = c >> 4, u = c & 15;
        if (u == 0) {   // refresh x2 registers for this v-block (uniform branch)
            #pragma unroll
            for (int q = 0; q < 4; ++q)
                #pragma unroll
                for (int kb = 0; kb < 2; ++kb) {
                    const uint4 hx = *(const uint4*)(x2b + q*128 + vb*32 + kb*16);
                    xq[q][kb][0]=bc(hx.x); xq[q][kb][1]=bc(hx.y);
                    xq[q][kb][2]=bc(hx.z); xq[q][kb][3]=bc(hx.w);
                }
        }
        B10 B1 = loadB(cb, 1, bo);                       // kb=1 of chunk c
        const uint2 h1n = *(const uint2*)(x1lds + (((u+1)&15)*128 + node)*4);

        // x1 broadcasts (packed f16 pairs)
        const h2 ps1 = bc(__builtin_amdgcn_perm(h1c.x, h1c.x, 0x01000100u));
        const h2 pv0 = bc(__builtin_amdgcn_perm(h1c.x, h1c.x, 0x03020302u));
        const h2 pv1 = bc(__builtin_amdgcn_perm(h1c.y, h1c.y, 0x01000100u));
        const h2 pv2 = bc(__builtin_amdgcn_perm(h1c.y, h1c.y, 0x03020302u));
        const h2 pva[3] = {pv0, pv1, pv2};

        // one k-block: A-gen (grouped, <=3 frags live) + 22 MFMA
        auto compute = [&](int kb, const B10& BB) __attribute__((always_inline)) {
            {
                F8 f0, f1;
                #pragma unroll
                for (int j = 0; j < 4; ++j) {
                    f0.h[j] = ps1 * xq[0][kb][j];
                    h2 d = pv0 * xq[1][kb][j];
                    d = __builtin_elementwise_fma(pv1, xq[2][kb][j], d);
                    f1.h[j] = __builtin_elementwise_fma(pv2, xq[3][kb][j], d);
                }
                acc[0][0] = __builtin_amdgcn_mfma_f32_32x32x16_f16(f0.v, BB.v[0], acc[0][0], 0,0,0);
                acc[1][0] = __builtin_amdgcn_mfma_f32_32x32x16_f16(f0.v, BB.v[1], acc[1][0], 0,0,0);
                acc[0][0] = __builtin_amdgcn_mfma_f32_32x32x16_f16(f1.v, BB.v[2], acc[0][0], 0,0,0);
                acc[1][0] = __builtin_amdgcn_mfma_f32_32x32x16_f16(f1.v, BB.v[3], acc[1][0], 0,0,0);
            }
            #pragma unroll
            for (int k = 0; k < 3; ++k) {
                const int k1 = (k+1) % 3, k2 = (k+2) % 3;
                F8 fa, fb, fc;
                #pragma unroll
                for (int j = 0; j < 4; ++j) {
                    fa.h[j] = ps1     * xq[1+k][kb][j];
                    fb.h[j] = pva[k]  * xq[0][kb][j];
                    h2 tx   = pva[k1] * xq[1+k2][kb][j];
                    fc.h[j] = __builtin_elementwise_fma(-pva[k2], xq[1+k1][kb][j], tx);
                }
                acc[0][1+k] = __builtin_amdgcn_mfma_f32_32x32x16_f16(fa.v, BB.v[4], acc[0][1+k], 0,0,0);
                acc[1][1+k] = __builtin_amdgcn_mfma_f32_32x32x16_f16(fa.v, BB.v[5], acc[1][1+k], 0,0,0);
                acc[0][1+k] = __builtin_amdgcn_mfma_f32_32x32x16_f16(fb.v, BB.v[6], acc[0][1+k], 0,0,0);
                acc[1][1+k] = __builtin_amdgcn_mfma_f32_32x32x16_f16(fb.v, BB.v[7], acc[1][1+k], 0,0,0);
                acc[0][1+k] = __builtin_amdgcn_mfma_f32_32x32x16_f16(fc.v, BB.v[8], acc[0][1+k], 0,0,0);
                acc[1][1+k] = __builtin_amdgcn_mfma_f32_32x32x16_f16(fc.v, BB.v[9], acc[1][1+k], 0,0,0);
            }
        };

        compute(0, B0);
        B10 B0n = loadB(cb + CHUNK_EL, 0, bo);           // kb=0 of chunk c+1
        compute(1, B1);
        B0 = B0n;
        h1c = h1n;
        cb += CHUNK_EL;
    }

    // epilogue: atomically accumulate (8 contributors/output)
    // C layout (32x32): col = lane&31, row = (r&3) + 8*(r>>2) + 4*(lane>>5)
    #pragma unroll
    for (int ct = 0; ct < 2; ++ct) {
        const int w = whalf*64 + ct*32 + l5;
        #pragma unroll
        for (int r = 0; r < 16; ++r) {
            const int n = t*128 + wv*32 + (r&3) + 8*(r>>2) + 4*kg2;
            float* op = out + (size_t)n*512;
            unsafeAtomicAdd(op + w,             acc[ct][0][r]);
            unsafeAtomicAdd(op + 128 + w*3 + 0, acc[ct][1][r]);
            unsafeAtomicAdd(op + 128 + w*3 + 1, acc[ct][2][r]);
            unsafeAtomicAdd(op + 128 + w*3 + 2, acc[ct][3][r]);
        }
    }
}

extern "C" void kernel_launch(void* const* d_in, const int* in_sizes, int n_in,
                              void* d_out, int out_size, void* d_ws, size_t ws_size,
                              hipStream_t stream)
{
    const float* x1s = (const float*)d_in[0];
    const float* x1v = (const float*)d_in[1];
    const float* x2s = (const float*)d_in[2];
    const float* x2v = (const float*)d_in[3];
    const float* w0  = (const float*)d_in[4];
    const float* w1  = (const float*)d_in[5];
    const float* w2  = (const float*)d_in[6];
    const float* w3  = (const float*)d_in[7];
    const float* w4  = (const float*)d_in[8];

    f16* wtb = (f16*)d_ws;
    f16* x1g = (f16*)((char*)d_ws + WT_BYTES);
    f16* x2g = (f16*)((char*)d_ws + WT_BYTES + X1_BYTES);
    float* out = (float*)d_out;

    pack_w_kernel<<<640, 256, 0, stream>>>(w0, w1, w2, w3, w4, wtb);
    pack_x_kernel<<<2176, 256, 0, stream>>>(x1s, x1v, x2s, x2v, x1g, x2g);
    hipMemsetAsync(d_out, 0, (size_t)out_size*sizeof(float), stream);
    tp_main<<<512, 256, 0, stream>>>(wtb, x1g, x2g, out);
}

// Round 15
// 276.018 us; speedup vs baseline: 1.1106x; 1.1106x over previous
//
#include <hip/hip_runtime.h>
#include <hip/hip_bf16.h>

// e3nn FullyConnectedTensorProduct (128x0e+128x1o)^2 -> 128x0e+128x1o, N=4096
// R15: R14 with the x1 prologue address bug fixed ((t*16+slice)*4096 added a
//      spurious whalf*4096 offset for half the slices; now (t*8+usec)*8192).
// ws layout: [WT f16 20MB][X1g f16 4MB][X2g f16 4MB]

typedef _Float16 f16;
typedef _Float16 f16x8 __attribute__((ext_vector_type(8)));
typedef _Float16 h2 __attribute__((ext_vector_type(2)));
typedef float f32x16 __attribute__((ext_vector_type(16)));
typedef unsigned u32;

#define WT_BYTES  (5u*4u*128u*4096u*2u)     // 20971520 B = 16 slices x 655360 el x 2B
#define X1_BYTES  (32u*8u*8192u*2u)         // 4194304  ([tile32][usec8][u16][n128][q4] f16)
#define SLICE_EL  655360u                    // 64 chunks x 10240
#define CHUNK_EL  10240u                     // [p5][kb2][w64][v16] f16 (20 KB)

__device__ __forceinline__ h2 bc(u32 x){ union{u32 u; h2 h;} c; c.u=x; return c.h; }

union F8 { h2 h[4]; f16x8 v; };

__device__ __forceinline__ void gl_lds16(const f16* g, f16* l) {
    __builtin_amdgcn_global_load_lds(
        (const __attribute__((address_space(1))) void*)g,
        (__attribute__((address_space(3))) void*)l,
        16, 0, 0);
}

// ---- prologue: weights f32 [u][v][w] -> WT[slice][c][p][kb][w64][v16] f16 ----
// (byte-identical to R13, HW-verified)
__global__ __launch_bounds__(256) void pack_w_kernel(
    const float* __restrict__ w0, const float* __restrict__ w1,
    const float* __restrict__ w2, const float* __restrict__ w3,
    const float* __restrict__ w4, f16* __restrict__ wt)
{
    __shared__ float tl[64][130];
    const int b = blockIdx.x;           // 640 = 5 paths x 128 u
    const int p = b >> 7;
    const int u = b & 127;
    const int usec = u >> 4;            // 0..7
    const int uin  = u & 15;
    const float* src = (p==0)?w0:(p==1)?w1:(p==2)?w2:(p==3)?w3:w4;
    const float scale = (p==0)?1.0f:(p==4)?0.40824829046386302f:0.57735026918962576f;

    for (int h = 0; h < 2; ++h) {       // two 64-v halves
        const float* spR = src + (size_t)u*16384 + (size_t)h*8192;
        #pragma unroll
        for (int k = 0; k < 8; ++k) {
            const int e4 = (k*256 + threadIdx.x) * 4;
            const float4 v4 = *(const float4*)(spR + e4);
            const int vi = e4 >> 7, w = e4 & 127;
            tl[vi][w+0]=v4.x; tl[vi][w+1]=v4.y; tl[vi][w+2]=v4.z; tl[vi][w+3]=v4.w;
        }
        __syncthreads();
        #pragma unroll
        for (int k = 0; k < 4; ++k) {
            const int cid = k*256 + threadIdx.x;     // 0..1023 8-el groups
            const int q     = cid & 3;               // v-8-group within chunk
            const int wg    = (cid >> 2) & 127;      // global w
            const int vbh   = cid >> 9;
            const int vb    = h*2 + vbh;
            const int c     = vb*16 + uin;
            const int kb    = q >> 1;
            const int h2i   = q & 1;
            const int whalf = wg >> 6;
            const int wl    = wg & 63;
            const int s     = usec*2 + whalf;
            f16x8 t8;
            #pragma unroll
            for (int j = 0; j < 8; ++j)
                t8[j] = (f16)(tl[vbh*32 + q*8 + j][wg] * scale);
            *(f16x8*)(wt + (size_t)s*SLICE_EL + (size_t)c*CHUNK_EL
                          + p*2048 + kb*1024 + wl*16 + h2i*8) = t8;
        }
        __syncthreads();
    }
}

// ---- prologue: pack x1 -> [tile32][usec8][u16][n128][q4]; x2 -> [n][q][v] ----
// (byte-identical to R13, HW-verified)
__global__ __launch_bounds__(256) void pack_x_kernel(
    const float* __restrict__ x1s, const float* __restrict__ x1v,
    const float* __restrict__ x2s, const float* __restrict__ x2v,
    f16* __restrict__ x1g, f16* __restrict__ x2g)
{
    if (blockIdx.x < 128) {
        __shared__ uint2 tl[128][33];
        const int nb = blockIdx.x;      // 32-node block
        #pragma unroll
        for (int k = 0; k < 16; ++k) {
            const int idx = k*256 + threadIdx.x;    // u fast
            const int u = idx & 127, nd = idx >> 7;
            const size_t i = (size_t)(nb*32 + nd)*128 + u;
            union { f16 h[4]; uint2 u2; } tp;
            tp.h[0] = (f16)x1s[i];
            tp.h[1] = (f16)x1v[i*3 + 0];
            tp.h[2] = (f16)x1v[i*3 + 1];
            tp.h[3] = (f16)x1v[i*3 + 2];
            tl[u][nd] = tp.u2;
        }
        __syncthreads();
        uint2* og = (uint2*)x1g;
        const int t = nb >> 2, nd0 = (nb & 3) * 32;   // tile of 128 nodes
        #pragma unroll
        for (int k = 0; k < 16; ++k) {
            const int idx = k*256 + threadIdx.x;    // nd fast
            const int u = idx >> 5, nd = idx & 31;
            og[(((t*8 + (u>>4))*16 + (u&15)) << 7) + nd0 + nd] = tl[u][nd];
        }
    } else {
        const int tt = (blockIdx.x - 128)*256 + threadIdx.x;
        const int n = tt >> 7, v = tt & 127;
        const size_t b = (size_t)n*512;
        const size_t i = (size_t)n*128 + v;
        x2g[b +   0 + v] = (f16)x2s[i];
        x2g[b + 128 + v] = (f16)x2v[i*3 + 0];
        x2g[b + 256 + v] = (f16)x2v[i*3 + 1];
        x2g[b + 384 + v] = (f16)x2v[i*3 + 2];
    }
}

// ---- main: 512 WGs = 32 node-tiles(128) x 16 slices(usec8 x whalf2), 256 thr
// slice s%8 on XCD s%8 (2 x 1.25MB/XCD, L2-resident). wave = 32n x 64w,
// 32x32x16 MFMA, acc[2ct][4ch] f32x16. 2 WG/CU, 8 waves/CU. R9 pipeline:
// body c = vmcnt(0); barrier; stage c+1 (gl_lds, zero VGPR cost); compute.
__global__ __launch_bounds__(256, 2) void tp_main(
    const f16* __restrict__ wt, const f16* __restrict__ x1g,
    const f16* __restrict__ x2g, float* __restrict__ out)
{
    __shared__ __align__(16) f16 wlds[2*CHUNK_EL];  // 40 KB double-buffer weights
    __shared__ __align__(16) f16 x1lds[8192];       // 16 KB [u16][n128][q4]

    const int tid  = threadIdx.x;
    const int lane = tid & 63;
    const int wv   = tid >> 6;       // 0..3
    const int l5   = lane & 31;
    const int kg2  = lane >> 5;

    const int b     = blockIdx.x;
    const int slice = b & 15;                     // XCD slice%8
    const int t     = b >> 4;                     // node tile 0..31
    const int usec  = slice >> 1;
    const int whalf = slice & 1;

    const f16* wstream = wt + (size_t)slice * SLICE_EL;
    const int bo = l5*16 + kg2*8;                 // per-lane B offset (els)

    // prologue: x1 slice (16KB) + weight chunk 0; full drain once
    {
        const f16* src = x1g + (size_t)(t*8 + usec) * 8192;   // FIXED (was +whalf*4096)
        #pragma unroll
        for (int r = 0; r < 4; ++r)
            gl_lds16(src + r*2048 + tid*8, x1lds + r*2048 + tid*8);
    }
    #pragma unroll
    for (int r = 0; r < 5; ++r)
        gl_lds16(wstream + r*2048 + tid*8, wlds + r*2048 + tid*8);
    __syncthreads();

    f32x16 acc[2][4];   // [ct][channel] = 128 regs (AGPR)
    #pragma unroll
    for (int c2 = 0; c2 < 2; ++c2)
        #pragma unroll
        for (int ch = 0; ch < 4; ++ch)
            #pragma unroll
            for (int r = 0; r < 16; ++r)
                acc[c2][ch][r] = 0.f;

    h2 xq[4][2][4];     // [q][kb][pair] = 32 regs
    const int node = wv*32 + l5;
    const f16* x2b = x2g + (size_t)(t*128 + node)*512 + kg2*8;
    const f16* wsrc = wstream + CHUNK_EL + tid*8;   // chunk 1 base

    auto body = [&](int cc, int buf) __attribute__((always_inline)) {
        const int u = cc & 15;
        // x2 refresh at v-block boundary (issued before drain)
        if (u == 0) {
            const int vb = cc >> 4;
            #pragma unroll
            for (int q = 0; q < 4; ++q)
                #pragma unroll
                for (int kb = 0; kb < 2; ++kb) {
                    const uint4 hx = *(const uint4*)(x2b + q*128 + vb*32 + kb*16);
                    xq[q][kb][0]=bc(hx.x); xq[q][kb][1]=bc(hx.y);
                    xq[q][kb][2]=bc(hx.z); xq[q][kb][3]=bc(hx.w);
                }
        }

        // wait for chunk cc (staged one body ago; latency hidden), sync
        asm volatile("s_waitcnt vmcnt(0)" ::: "memory");
        __builtin_amdgcn_s_barrier();
        __builtin_amdgcn_sched_barrier(0);

        // stage chunk cc+1 into buf^1 (after barrier: race-free; no VGPR cost)
        if (cc < 63) {
            f16* dc = wlds + (buf^1)*CHUNK_EL + tid*8;
            #pragma unroll
            for (int r = 0; r < 5; ++r)
                gl_lds16(wsrc + r*2048, dc + r*2048);
        }
        wsrc += CHUNK_EL;

        // x1 broadcasts (packed f16 pairs)
        const uint2 h1 = *(const uint2*)(x1lds + u*512 + node*4);
        const h2 ps1 = bc(__builtin_amdgcn_perm(h1.x, h1.x, 0x01000100u));
        const h2 pv0 = bc(__builtin_amdgcn_perm(h1.x, h1.x, 0x03020302u));
        const h2 pv1 = bc(__builtin_amdgcn_perm(h1.y, h1.y, 0x01000100u));
        const h2 pv2 = bc(__builtin_amdgcn_perm(h1.y, h1.y, 0x03020302u));
        const h2 pva[3] = {pv0, pv1, pv2};

        const f16* wb = wlds + buf*CHUNK_EL;
        #pragma unroll
        for (int kb = 0; kb < 2; ++kb) {
            // A-gen for this k-block (shared by both ct)
            F8 f0, f1, fa[3], fb[3], fc[3];
            #pragma unroll
            for (int j = 0; j < 4; ++j) {
                f0.h[j] = ps1 * xq[0][kb][j];
                h2 d = pv0 * xq[1][kb][j];
                d = __builtin_elementwise_fma(pv1, xq[2][kb][j], d);
                f1.h[j] = __builtin_elementwise_fma(pv2, xq[3][kb][j], d);
            }
            #pragma unroll
            for (int k = 0; k < 3; ++k) {
                const int k1 = (k+1) % 3, k2 = (k+2) % 3;
                #pragma unroll
                for (int j = 0; j < 4; ++j) {
                    fa[k].h[j] = ps1    * xq[1+k][kb][j];
                    fb[k].h[j] = pva[k] * xq[0][kb][j];
                    h2 tx = pva[k1] * xq[1+k2][kb][j];
                    fc[k].h[j] = __builtin_elementwise_fma(-pva[k2], xq[1+k1][kb][j], tx);
                }
            }
            // per col-tile: 5 B-frags (contiguous 1KB reads) + 11 MFMA
            #pragma unroll
            for (int ct = 0; ct < 2; ++ct) {
                const f16* fbp = wb + kb*1024 + ct*512 + bo;
                const f16x8 b0 = *(const f16x8*)(fbp +    0);
                const f16x8 b1 = *(const f16x8*)(fbp + 2048);
                const f16x8 b2 = *(const f16x8*)(fbp + 4096);
                const f16x8 b3 = *(const f16x8*)(fbp + 6144);
                const f16x8 b4 = *(const f16x8*)(fbp + 8192);
                acc[ct][0] = __builtin_amdgcn_mfma_f32_32x32x16_f16(f0.v, b0, acc[ct][0], 0,0,0);
                acc[ct][0] = __builtin_amdgcn_mfma_f32_32x32x16_f16(f1.v, b1, acc[ct][0], 0,0,0);
                #pragma unroll
                for (int k = 0; k < 3; ++k) {
                    acc[ct][1+k] = __builtin_amdgcn_mfma_f32_32x32x16_f16(fa[k].v, b2, acc[ct][1+k], 0,0,0);
                    acc[ct][1+k] = __builtin_amdgcn_mfma_f32_32x32x16_f16(fb[k].v, b3, acc[ct][1+k], 0,0,0);
                    acc[ct][1+k] = __builtin_amdgcn_mfma_f32_32x32x16_f16(fc[k].v, b4, acc[ct][1+k], 0,0,0);
                }
            }
        }
    };

    for (int c2b = 0; c2b < 64; c2b += 2) {
        body(c2b + 0, 0);
        body(c2b + 1, 1);
    }

    // epilogue: atomically accumulate (8 contributors/output)
    // C layout (32x32): col = lane&31, row = (r&3) + 8*(r>>2) + 4*(lane>>5)
    #pragma unroll
    for (int ct = 0; ct < 2; ++ct) {
        const int w = whalf*64 + ct*32 + l5;
        #pragma unroll
        for (int r = 0; r < 16; ++r) {
            const int n = t*128 + wv*32 + (r&3) + 8*(r>>2) + 4*kg2;
            float* op = out + (size_t)n*512;
            unsafeAtomicAdd(op + w,             acc[ct][0][r]);
            unsafeAtomicAdd(op + 128 + w*3 + 0, acc[ct][1][r]);
            unsafeAtomicAdd(op + 128 + w*3 + 1, acc[ct][2][r]);
            unsafeAtomicAdd(op + 128 + w*3 + 2, acc[ct][3][r]);
        }
    }
}

extern "C" void kernel_launch(void* const* d_in, const int* in_sizes, int n_in,
                              void* d_out, int out_size, void* d_ws, size_t ws_size,
                              hipStream_t stream)
{
    const float* x1s = (const float*)d_in[0];
    const float* x1v = (const float*)d_in[1];
    const float* x2s = (const float*)d_in[2];
    const float* x2v = (const float*)d_in[3];
    const float* w0  = (const float*)d_in[4];
    const float* w1  = (const float*)d_in[5];
    const float* w2  = (const float*)d_in[6];
    const float* w3  = (const float*)d_in[7];
    const float* w4  = (const float*)d_in[8];

    f16* wtb = (f16*)d_ws;
    f16* x1g = (f16*)((char*)d_ws + WT_BYTES);
    f16* x2g = (f16*)((char*)d_ws + WT_BYTES + X1_BYTES);
    float* out = (float*)d_out;

    pack_w_kernel<<<640, 256, 0, stream>>>(w0, w1, w2, w3, w4, wtb);
    pack_x_kernel<<<2176, 256, 0, stream>>>(x1s, x1v, x2s, x2v, x1g, x2g);
    hipMemsetAsync(d_out, 0, (size_t)out_size*sizeof(float), stream);
    tp_main<<<512, 256, 0, stream>>>(wtb, x1g, x2g, out);
}